// Round 4
// baseline (45.520 us; speedup 1.0000x reference)
//
#include <hip/hip_runtime.h>

#define RADIUS 4
#define KK 81
#define HWP 4096

typedef _Float16 f16x8 __attribute__((ext_vector_type(8)));
typedef _Float16 f16x4 __attribute__((ext_vector_type(4)));
typedef float    f32x4 __attribute__((ext_vector_type(4)));

// ws byte-offset layout (f16 channel-last staging)
#define OFF_F1T  0u
#define OFF_L0   4194304u
#define OFF_L1   8388608u
#define OFF_L2   9437184u
#define OFF_L3   9699328u
#define OFF_ZPAD 9764864u        // 512 B of zeros (filled by stage_kernel block 0)
#define OFF_END  9765376u

// ---------- fused staging: all 5 transposes (f32 [B,256,S] -> f16 [B,S,256]) ----------
__global__ __launch_bounds__(256) void stage_kernel(
    const float* __restrict__ f1, const float* __restrict__ l0,
    const float* __restrict__ l1, const float* __restrict__ l2,
    const float* __restrict__ l3, char* __restrict__ wsB)
{
    __shared__ float tile[32][36];   // pad 36: 16B-aligned rows, 2-way max LDS aliasing
    const int bx = blockIdx.x;    // 0..297
    const int b  = blockIdx.z;
    const int r0 = blockIdx.y * 32;
    const int t  = threadIdx.x;   // 0..255
    if (bx == 0 && blockIdx.y == 0 && b == 0 && t < 128)
        ((float*)(wsB + OFF_ZPAD))[t] = 0.0f;   // zero pad record
    const float* src; _Float16* dst; int S, s0i;
    if (bx < 128)      { src = f1; dst = (_Float16*)(wsB + OFF_F1T); S = 4096; s0i = bx; }
    else if (bx < 256) { src = l0; dst = (_Float16*)(wsB + OFF_L0);  S = 4096; s0i = bx - 128; }
    else if (bx < 288) { src = l1; dst = (_Float16*)(wsB + OFF_L1);  S = 1024; s0i = bx - 256; }
    else if (bx < 296) { src = l2; dst = (_Float16*)(wsB + OFF_L2);  S = 256;  s0i = bx - 288; }
    else               { src = l3; dst = (_Float16*)(wsB + OFF_L3);  S = 64;   s0i = bx - 296; }
    const int s0 = s0i * 32;
    src += (size_t)b * 256 * S;
    dst += (size_t)b * S * 256;
    {
        const int row = t >> 3, cg = t & 7;
        *(f32x4*)&tile[row][cg * 4] =
            *(const f32x4*)&src[(size_t)(r0 + row) * S + s0 + cg * 4];
    }
    __syncthreads();
    {
        const int sidx = t >> 3, chg = t & 7;
        f16x4 o;
        o[0] = (_Float16)tile[chg * 4 + 0][sidx];
        o[1] = (_Float16)tile[chg * 4 + 1][sidx];
        o[2] = (_Float16)tile[chg * 4 + 2][sidx];
        o[3] = (_Float16)tile[chg * 4 + 3][sidx];
        *(f16x4*)&dst[(size_t)(s0 + sidx) * 256 + r0 + chg * 4] = o;
    }
}

// ---------- main: 8x4-px tiles, BARRIER-FREE per-wave gather-GEMM ----------
// 1024 blocks (256 tiles x 4 lvls), 4 waves. Each wave independently walks units
// u = wid, wid+4, ... of the window's linear unit list with an asm-load ping-pong
// (16 loads in flight, vmcnt(8) gate — R0-proven mechanism). Each 8-KB unit is
// consumed by BOTH 16-px A-sets in registers (16 MFMA / 8 loads), so gather
// volume matches the R2 LDS-shared scheme but with ZERO in-loop barriers:
// latency is hidden by cross-block wave TLP, not lockstep prefetch distance.
__global__ __launch_bounds__(256, 2) void corr_mfma_kernel(
    const char* __restrict__ wsB,
    const float* __restrict__ coords,
    float* __restrict__ out)           // [B,324,4096]
{
    __shared__ float sD[32][104];      // per-px 10x10 window dots
    __shared__ int   sIx[32], sIy[32];
    __shared__ float sW[32][4];
    __shared__ int   sBox[5];          // rlo, cfi, ntw, ntot, inv

    const int bx   = blockIdx.x;                  // 0..255
    const int lvl  = blockIdx.y;                  // 0..3
    const int tile = ((bx & 7) << 5) | (bx >> 3); // XCD swizzle (bijective on 256)
    const int b    = tile >> 7;
    const int t7   = tile & 127;                  // 128 tiles per batch: 16 rows x 8 cols
    const int tr4  = (t7 >> 3) << 2;              // tile pixel-row base (4 tall)
    const int tc8  = (t7 & 7) << 3;               // tile pixel-col base (8 wide)
    const int t    = threadIdx.x;                 // 0..255
    const int l    = t & 63;
    const int wid  = t >> 6;                      // wave 0..3

    const int sh = 6 - lvl;
    const int W2 = 1 << sh;

    for (int i = t; i < 32 * 104; i += 256)
        ((float*)sD)[i] = 0.0f;

    if (t < 32) {
        const int hwc = ((tr4 + (t >> 3)) << 6) + tc8 + (t & 7);
        const float sc = 1.0f / (float)(1 << lvl);
        const float xs = coords[((size_t)b * 2 + 0) * HWP + hwc] * sc;
        const float ys = coords[((size_t)b * 2 + 1) * HWP + hwc] * sc;
        const float x0f = floorf(xs), y0f = floorf(ys);
        sIx[t] = (int)x0f; sIy[t] = (int)y0f;
        const float fx = xs - x0f, fy = ys - y0f;
        sW[t][0] = (1.f - fx) * (1.f - fy);
        sW[t][1] = fx * (1.f - fy);
        sW[t][2] = (1.f - fx) * fy;
        sW[t][3] = fx * fy;
    }
    __syncthreads();
    if (t == 0) {
        int rlo = 1 << 20, rhi = -(1 << 20), clo = 1 << 20, chi = -(1 << 20);
        for (int px = 0; px < 32; ++px) {
            rlo = min(rlo, sIy[px]); rhi = max(rhi, sIy[px]);
            clo = min(clo, sIx[px]); chi = max(chi, sIx[px]);
        }
        const int rl = max(rlo - RADIUS, 0);
        const int rh = min(rhi + RADIUS + 1, W2 - 1);
        const int cf = max(clo - RADIUS, 0);
        const int ce = min(chi + RADIUS + 1, W2 - 1);
        const int nr = rh - rl + 1;
        const int nt = (ce >= cf) ? ((ce - cf + 16) >> 4) : 0;
        sBox[0] = rl;
        sBox[1] = cf;
        sBox[2] = nt;
        sBox[3] = (nr > 0) ? nr * nt : 0;
        sBox[4] = 65535 / max(nt, 1) + 1;     // exact u/nt = (u*inv)>>16 for u<512,nt<=8
    }

    // A fragments for BOTH 16-px sets (verified R9 mapping): lane l = px (l&15), k-chunk (l>>4)
    const int hwA0 = ((tr4 + ((l & 15) >> 3)) << 6) + tc8 + (l & 7);          // px 0..15
    const int hwA1 = ((tr4 + 2 + ((l & 15) >> 3)) << 6) + tc8 + (l & 7);      // px 16..31
    const char* ap0 = wsB + OFF_F1T + ((size_t)(b * HWP + hwA0)) * 512 + ((l >> 4) << 4);
    const char* ap1 = wsB + OFF_F1T + ((size_t)(b * HWP + hwA1)) * 512 + ((l >> 4) << 4);
    const f16x8 a00 = __builtin_bit_cast(f16x8, *(const f32x4*)(ap0));
    const f16x8 a01 = __builtin_bit_cast(f16x8, *(const f32x4*)(ap0 + 64));
    const f16x8 a02 = __builtin_bit_cast(f16x8, *(const f32x4*)(ap0 + 128));
    const f16x8 a03 = __builtin_bit_cast(f16x8, *(const f32x4*)(ap0 + 192));
    const f16x8 a04 = __builtin_bit_cast(f16x8, *(const f32x4*)(ap0 + 256));
    const f16x8 a05 = __builtin_bit_cast(f16x8, *(const f32x4*)(ap0 + 320));
    const f16x8 a06 = __builtin_bit_cast(f16x8, *(const f32x4*)(ap0 + 384));
    const f16x8 a07 = __builtin_bit_cast(f16x8, *(const f32x4*)(ap0 + 448));
    const f16x8 a10 = __builtin_bit_cast(f16x8, *(const f32x4*)(ap1));
    const f16x8 a11 = __builtin_bit_cast(f16x8, *(const f32x4*)(ap1 + 64));
    const f16x8 a12 = __builtin_bit_cast(f16x8, *(const f32x4*)(ap1 + 128));
    const f16x8 a13 = __builtin_bit_cast(f16x8, *(const f32x4*)(ap1 + 192));
    const f16x8 a14 = __builtin_bit_cast(f16x8, *(const f32x4*)(ap1 + 256));
    const f16x8 a15 = __builtin_bit_cast(f16x8, *(const f32x4*)(ap1 + 320));
    const f16x8 a16 = __builtin_bit_cast(f16x8, *(const f32x4*)(ap1 + 384));
    const f16x8 a17 = __builtin_bit_cast(f16x8, *(const f32x4*)(ap1 + 448));
    __syncthreads();                      // publish sBox (also drains A-loads)

    const int rlo = sBox[0], cfi = sBox[1], ntw = sBox[2];
    const int ntot = sBox[3], inv = sBox[4];
    const unsigned lvbase = ((lvl == 0) ? OFF_L0 : (lvl == 1) ? OFF_L1
                           : (lvl == 2) ? OFF_L2 : OFF_L3)
                          + (((unsigned)b << (2 * sh)) << 9);
    const int coff = l & 15;
    const int ksub = (l >> 4) << 4;
    const unsigned zp = OFF_ZPAD + (unsigned)ksub;

    const int pg0 = (l >> 4) << 2;       // scatter pixels of A-set 0 (this lane)
    const int pg1 = 16 + pg0;            // scatter pixels of A-set 1
    const int iy0 = sIy[pg0 + 0], ix0 = sIx[pg0 + 0];
    const int iy1 = sIy[pg0 + 1], ix1 = sIx[pg0 + 1];
    const int iy2 = sIy[pg0 + 2], ix2 = sIx[pg0 + 2];
    const int iy3 = sIy[pg0 + 3], ix3 = sIx[pg0 + 3];
    const int iy4 = sIy[pg1 + 0], ix4 = sIx[pg1 + 0];
    const int iy5 = sIy[pg1 + 1], ix5 = sIx[pg1 + 1];
    const int iy6 = sIy[pg1 + 2], ix6 = sIx[pg1 + 2];
    const int iy7 = sIy[pg1 + 3], ix7 = sIx[pg1 + 3];

    // drain all compiler-tracked VMEM so in-loop vmcnt counts ONLY our asm loads
    asm volatile("s_waitcnt vmcnt(0)" ::: "memory");
    __builtin_amdgcn_sched_barrier(0);

#define DECODE(U_, RR_, JJ_) { const unsigned q__ = ((unsigned)((U_) * inv)) >> 16; \
        JJ_ = (U_) - (int)q__ * ntw; RR_ = rlo + (int)q__; }

// issue one unit's 8 loads via volatile asm (compiler cannot sink/coalesce these)
#define ISSUE(R_, J_, B0, B1, B2, B3, B4, B5, B6, B7) { \
        const int col_ = cfi + ((J_) << 4) + coff; \
        const bool ok_ = (unsigned)col_ < (unsigned)W2; \
        const unsigned cb_ = ok_ ? (lvbase + ((unsigned)(((R_) << sh) + col_) << 9) + (unsigned)ksub) : zp; \
        const char* gp_ = wsB + cb_; \
        asm volatile("global_load_dwordx4 %0, %1, off"            : "=v"(B0) : "v"(gp_)); \
        asm volatile("global_load_dwordx4 %0, %1, off offset:64"  : "=v"(B1) : "v"(gp_)); \
        asm volatile("global_load_dwordx4 %0, %1, off offset:128" : "=v"(B2) : "v"(gp_)); \
        asm volatile("global_load_dwordx4 %0, %1, off offset:192" : "=v"(B3) : "v"(gp_)); \
        asm volatile("global_load_dwordx4 %0, %1, off offset:256" : "=v"(B4) : "v"(gp_)); \
        asm volatile("global_load_dwordx4 %0, %1, off offset:320" : "=v"(B5) : "v"(gp_)); \
        asm volatile("global_load_dwordx4 %0, %1, off offset:384" : "=v"(B6) : "v"(gp_)); \
        asm volatile("global_load_dwordx4 %0, %1, off offset:448" : "=v"(B7) : "v"(gp_)); }

#define WAITV8 { asm volatile("s_waitcnt vmcnt(8)" ::: "memory"); __builtin_amdgcn_sched_barrier(0); }
#define WAITV0 { asm volatile("s_waitcnt vmcnt(0)" ::: "memory"); __builtin_amdgcn_sched_barrier(0); }

// consume one unit against BOTH A-sets: 16 MFMA, scatter 8 px
#define CONSUMET(R_, J_, B0, B1, B2, B3, B4, B5, B6, B7) { \
        f32x4 ac00 = {0.f,0.f,0.f,0.f}, ac01 = {0.f,0.f,0.f,0.f}; \
        f32x4 ac10 = {0.f,0.f,0.f,0.f}, ac11 = {0.f,0.f,0.f,0.f}; \
        ac00 = __builtin_amdgcn_mfma_f32_16x16x32_f16(a00, __builtin_bit_cast(f16x8, B0), ac00, 0, 0, 0); \
        ac10 = __builtin_amdgcn_mfma_f32_16x16x32_f16(a10, __builtin_bit_cast(f16x8, B0), ac10, 0, 0, 0); \
        ac01 = __builtin_amdgcn_mfma_f32_16x16x32_f16(a01, __builtin_bit_cast(f16x8, B1), ac01, 0, 0, 0); \
        ac11 = __builtin_amdgcn_mfma_f32_16x16x32_f16(a11, __builtin_bit_cast(f16x8, B1), ac11, 0, 0, 0); \
        ac00 = __builtin_amdgcn_mfma_f32_16x16x32_f16(a02, __builtin_bit_cast(f16x8, B2), ac00, 0, 0, 0); \
        ac10 = __builtin_amdgcn_mfma_f32_16x16x32_f16(a12, __builtin_bit_cast(f16x8, B2), ac10, 0, 0, 0); \
        ac01 = __builtin_amdgcn_mfma_f32_16x16x32_f16(a03, __builtin_bit_cast(f16x8, B3), ac01, 0, 0, 0); \
        ac11 = __builtin_amdgcn_mfma_f32_16x16x32_f16(a13, __builtin_bit_cast(f16x8, B3), ac11, 0, 0, 0); \
        ac00 = __builtin_amdgcn_mfma_f32_16x16x32_f16(a04, __builtin_bit_cast(f16x8, B4), ac00, 0, 0, 0); \
        ac10 = __builtin_amdgcn_mfma_f32_16x16x32_f16(a14, __builtin_bit_cast(f16x8, B4), ac10, 0, 0, 0); \
        ac01 = __builtin_amdgcn_mfma_f32_16x16x32_f16(a05, __builtin_bit_cast(f16x8, B5), ac01, 0, 0, 0); \
        ac11 = __builtin_amdgcn_mfma_f32_16x16x32_f16(a15, __builtin_bit_cast(f16x8, B5), ac11, 0, 0, 0); \
        ac00 = __builtin_amdgcn_mfma_f32_16x16x32_f16(a06, __builtin_bit_cast(f16x8, B6), ac00, 0, 0, 0); \
        ac10 = __builtin_amdgcn_mfma_f32_16x16x32_f16(a16, __builtin_bit_cast(f16x8, B6), ac10, 0, 0, 0); \
        ac01 = __builtin_amdgcn_mfma_f32_16x16x32_f16(a07, __builtin_bit_cast(f16x8, B7), ac01, 0, 0, 0); \
        ac11 = __builtin_amdgcn_mfma_f32_16x16x32_f16(a17, __builtin_bit_cast(f16x8, B7), ac11, 0, 0, 0); \
        const f32x4 s0 = ac00 + ac01; \
        const f32x4 s1 = ac10 + ac11; \
        const int col_ = cfi + ((J_) << 4) + coff; \
        const int p0 = (R_) - iy0 + RADIUS, q0 = col_ - ix0 + RADIUS; \
        if ((unsigned)p0 < 10u && (unsigned)q0 < 10u) sD[pg0 + 0][p0 * 10 + q0] = s0[0]; \
        const int p1 = (R_) - iy1 + RADIUS, q1 = col_ - ix1 + RADIUS; \
        if ((unsigned)p1 < 10u && (unsigned)q1 < 10u) sD[pg0 + 1][p1 * 10 + q1] = s0[1]; \
        const int p2 = (R_) - iy2 + RADIUS, q2 = col_ - ix2 + RADIUS; \
        if ((unsigned)p2 < 10u && (unsigned)q2 < 10u) sD[pg0 + 2][p2 * 10 + q2] = s0[2]; \
        const int p3 = (R_) - iy3 + RADIUS, q3 = col_ - ix3 + RADIUS; \
        if ((unsigned)p3 < 10u && (unsigned)q3 < 10u) sD[pg0 + 3][p3 * 10 + q3] = s0[3]; \
        const int p4 = (R_) - iy4 + RADIUS, q4 = col_ - ix4 + RADIUS; \
        if ((unsigned)p4 < 10u && (unsigned)q4 < 10u) sD[pg1 + 0][p4 * 10 + q4] = s1[0]; \
        const int p5 = (R_) - iy5 + RADIUS, q5 = col_ - ix5 + RADIUS; \
        if ((unsigned)p5 < 10u && (unsigned)q5 < 10u) sD[pg1 + 1][p5 * 10 + q5] = s1[1]; \
        const int p6 = (R_) - iy6 + RADIUS, q6 = col_ - ix6 + RADIUS; \
        if ((unsigned)p6 < 10u && (unsigned)q6 < 10u) sD[pg1 + 2][p6 * 10 + q6] = s1[2]; \
        const int p7 = (R_) - iy7 + RADIUS, q7 = col_ - ix7 + RADIUS; \
        if ((unsigned)p7 < 10u && (unsigned)q7 < 10u) sD[pg1 + 3][p7 * 10 + q7] = s1[3]; }

    // per-wave ping-pong over units u = wid, wid+4, ... (no barriers in loop)
    {
        f32x4 X0, X1, X2, X3, X4, X5, X6, X7;
        f32x4 Y0, Y1, Y2, Y3, Y4, Y5, Y6, Y7;
        int ua = wid;
        if (ua < ntot) {
            int ra, ja, rb, jb;
            DECODE(ua, ra, ja);
            ISSUE(ra, ja, X0, X1, X2, X3, X4, X5, X6, X7);
            int ub = ua + 4;
            for (;;) {
                const bool bv = (ub < ntot);
                if (bv) { DECODE(ub, rb, jb); ISSUE(rb, jb, Y0, Y1, Y2, Y3, Y4, Y5, Y6, Y7); WAITV8; }
                else    { WAITV0; }
                CONSUMET(ra, ja, X0, X1, X2, X3, X4, X5, X6, X7);
                if (!bv) break;
                ua = ub + 4;
                const bool av = (ua < ntot);
                if (av) { DECODE(ua, ra, ja); ISSUE(ra, ja, X0, X1, X2, X3, X4, X5, X6, X7); WAITV8; }
                else    { WAITV0; }
                CONSUMET(rb, jb, Y0, Y1, Y2, Y3, Y4, Y5, Y6, Y7);
                if (!av) break;
                ub = ua + 4;
            }
        }
    }
#undef DECODE
#undef ISSUE
#undef WAITV8
#undef WAITV0
#undef CONSUMET
    __syncthreads();

    // bilinear combine + store (this level's 81 channels, 32 pixels)
    for (int j = t; j < 32 * KK; j += 256) {
        const int px = j & 31;
        const int k  = j >> 5;           // 0..80
        const int p  = (k * 57) >> 9;    // k/9
        const int q  = k - p * 9;
        const int bi = p * 10 + q;
        const float* dd = sD[px];
        const float v = (sW[px][0] * dd[bi]      + sW[px][1] * dd[bi + 1] +
                         sW[px][2] * dd[bi + 10] + sW[px][3] * dd[bi + 11]) * 0.0625f;
        const int hwp = ((tr4 + (px >> 3)) << 6) + tc8 + (px & 7);
        out[((size_t)b * 324 + lvl * KK + k) * HWP + hwp] = v;
    }
}

// ---------- fallback (Round-2 verified, original layouts) ----------
__global__ __launch_bounds__(128) void corr_level_kernel(
    const float* __restrict__ f1, const float* __restrict__ f2,
    const float* __restrict__ coords, float* __restrict__ out,
    int H2, int W2, float scale, int lvl)
{
    __shared__ float sf1[256];
    __shared__ float sDl[100];
    const int pix = blockIdx.x;
    const int b   = pix >> 12;
    const int hw  = pix & 4095;
    const int t   = threadIdx.x;
    for (int c = t; c < 256; c += 128)
        sf1[c] = f1[((size_t)b * 256 + c) * 4096 + hw];
    __syncthreads();
    const float xs = coords[((size_t)b * 2 + 0) * 4096 + hw] * scale;
    const float ys = coords[((size_t)b * 2 + 1) * 4096 + hw] * scale;
    const float x0f = floorf(xs), y0f = floorf(ys);
    const float fx = xs - x0f, fy = ys - y0f;
    const int ix0 = (int)x0f, iy0 = (int)y0f;
    if (t < 100) {
        const int p = t / 10, q = t - p * 10;
        const int row = iy0 - 4 + p, col = ix0 - 4 + q;
        float acc = 0.0f;
        if (row >= 0 && row < H2 && col >= 0 && col < W2) {
            const size_t step = (size_t)H2 * W2;
            const size_t base = (size_t)b * 256 * step + (size_t)row * W2 + col;
            #pragma unroll 4
            for (int c = 0; c < 256; ++c)
                acc += f2[base + (size_t)c * step] * sf1[c];
        }
        sDl[t] = acc;
    }
    __syncthreads();
    if (t < 81) {
        const int p = t / 9, q = t - p * 9;
        const float d00 = sDl[p * 10 + q];
        const float d01 = sDl[p * 10 + q + 1];
        const float d10 = sDl[p * 10 + q + 10];
        const float d11 = sDl[p * 10 + q + 11];
        const float v = (1.0f - fy) * ((1.0f - fx) * d00 + fx * d01)
                      + fy * ((1.0f - fx) * d10 + fx * d11);
        out[((size_t)b * 324 + (size_t)lvl * 81 + t) * 4096 + hw] = v * 0.0625f;
    }
}

extern "C" void kernel_launch(void* const* d_in, const int* in_sizes, int n_in,
                              void* d_out, int out_size, void* d_ws, size_t ws_size,
                              hipStream_t stream) {
    (void)out_size;
    const float* f1     = (const float*)d_in[0];
    const float* f2l[4] = {(const float*)d_in[1], (const float*)d_in[2],
                           (const float*)d_in[3], (const float*)d_in[4]};
    const float* coords = (const float*)d_in[5];

    // Size-based identification (input order proved unreliable in R1).
    {
        int nbig = 0;
        for (int i = 0; i < n_in; ++i) {
            const int sz = in_sizes[i];
            if (sz == 2097152) {
                if (nbig == 0) f1 = (const float*)d_in[i];
                else           f2l[0] = (const float*)d_in[i];
                ++nbig;
            }
            else if (sz == 524288) f2l[1] = (const float*)d_in[i];
            else if (sz == 131072) f2l[2] = (const float*)d_in[i];
            else if (sz ==  32768) f2l[3] = (const float*)d_in[i];
            else if (sz ==  16384) coords = (const float*)d_in[i];
        }
    }
    float* out = (float*)d_out;
    char*  wsB = (char*)d_ws;

    if (ws_size >= (size_t)OFF_END) {
        stage_kernel<<<dim3(298, 8, 2), dim3(256, 1, 1), 0, stream>>>(
            f1, f2l[0], f2l[1], f2l[2], f2l[3], wsB);
        corr_mfma_kernel<<<dim3(256, 4, 1), 256, 0, stream>>>(wsB, coords, out);
    } else {
        for (int lvl = 0; lvl < 4; ++lvl) {
            const int W2 = 64 >> lvl;
            const float scale = 1.0f / (float)(1 << lvl);
            corr_level_kernel<<<8192, 128, 0, stream>>>(
                f1, f2l[lvl], coords, out, W2, W2, scale, lvl);
        }
    }
}

// Round 5
// 45.182 us; speedup vs baseline: 1.0075x; 1.0075x over previous
//
#include <hip/hip_runtime.h>

#define RADIUS 4
#define KK 81
#define HWP 4096

typedef _Float16 f16x8 __attribute__((ext_vector_type(8)));
typedef _Float16 f16x4 __attribute__((ext_vector_type(4)));
typedef float    f32x4 __attribute__((ext_vector_type(4)));

// ws byte-offset layout (f16 channel-last staging)
#define OFF_F1T  0u
#define OFF_L0   4194304u
#define OFF_L1   8388608u
#define OFF_L2   9437184u
#define OFF_L3   9699328u
#define OFF_ZPAD 9764864u        // 512 B of zeros (filled by stage_kernel block 0)
#define OFF_END  9765376u

// ---------- fused staging: all 5 transposes (f32 [B,256,S] -> f16 [B,S,256]) ----------
__global__ __launch_bounds__(256) void stage_kernel(
    const float* __restrict__ f1, const float* __restrict__ l0,
    const float* __restrict__ l1, const float* __restrict__ l2,
    const float* __restrict__ l3, char* __restrict__ wsB)
{
    __shared__ float tile[32][36];   // pad 36: 16B-aligned rows, 2-way max LDS aliasing
    const int bx = blockIdx.x;    // 0..297
    const int b  = blockIdx.z;
    const int r0 = blockIdx.y * 32;
    const int t  = threadIdx.x;   // 0..255
    if (bx == 0 && blockIdx.y == 0 && b == 0 && t < 128)
        ((float*)(wsB + OFF_ZPAD))[t] = 0.0f;   // zero pad record
    const float* src; _Float16* dst; int S, s0i;
    if (bx < 128)      { src = f1; dst = (_Float16*)(wsB + OFF_F1T); S = 4096; s0i = bx; }
    else if (bx < 256) { src = l0; dst = (_Float16*)(wsB + OFF_L0);  S = 4096; s0i = bx - 128; }
    else if (bx < 288) { src = l1; dst = (_Float16*)(wsB + OFF_L1);  S = 1024; s0i = bx - 256; }
    else if (bx < 296) { src = l2; dst = (_Float16*)(wsB + OFF_L2);  S = 256;  s0i = bx - 288; }
    else               { src = l3; dst = (_Float16*)(wsB + OFF_L3);  S = 64;   s0i = bx - 296; }
    const int s0 = s0i * 32;
    src += (size_t)b * 256 * S;
    dst += (size_t)b * S * 256;
    {
        const int row = t >> 3, cg = t & 7;
        *(f32x4*)&tile[row][cg * 4] =
            *(const f32x4*)&src[(size_t)(r0 + row) * S + s0 + cg * 4];
    }
    __syncthreads();
    {
        const int sidx = t >> 3, chg = t & 7;
        f16x4 o;
        o[0] = (_Float16)tile[chg * 4 + 0][sidx];
        o[1] = (_Float16)tile[chg * 4 + 1][sidx];
        o[2] = (_Float16)tile[chg * 4 + 2][sidx];
        o[3] = (_Float16)tile[chg * 4 + 3][sidx];
        *(f16x4*)&dst[(size_t)(s0 + sidx) * 256 + r0 + chg * 4] = o;
    }
}

// ---------- main: 8x4-px tiles, barrier-free per-wave gather-GEMM ----------
// R5 change: XCD-CLUSTERED tile mapping (inverse of the GEMM swizzle). All rounds
// R2-R4 rode a ~7 TB/s ceiling = Infinity-Cache BW: the scattered mapping gave each
// XCD a ~10MB working set (>4MiB L2) so the 20x window-overlap reuse was served by
// L3. Now bx&7 -> XCD owns one (batch, 4-tile-row band): per-XCD working set
// ~2.1MB fits L2; reuse runs at L2 speed, L3 sees only the ~10MB compulsory pass.
// (grid-x stride 256 == 0 mod 8, so all 4 levels of a band share the XCD.)
__global__ __launch_bounds__(256, 2) void corr_mfma_kernel(
    const char* __restrict__ wsB,
    const float* __restrict__ coords,
    float* __restrict__ out)           // [B,324,4096]
{
    __shared__ float sD[32][104];      // per-px 10x10 window dots
    __shared__ int   sIx[32], sIy[32];
    __shared__ float sW[32][4];
    __shared__ int   sBox[5];          // rlo, cfi, ntw, ntot, inv

    const int bx   = blockIdx.x;                  // 0..255
    const int lvl  = blockIdx.y;                  // 0..3
    const int xcd  = bx & 7;                      // dispatch round-robin -> XCD id
    const int idx  = bx >> 3;                     // 0..31 within XCD
    const int b    = xcd >> 2;                    // batch: XCD 0-3 -> b0, 4-7 -> b1
    const int trow = ((xcd & 3) << 2) + (idx >> 3);  // tile row 0..15 (band of 4)
    const int tcol = idx & 7;                     // tile col 0..7
    const int tr4  = trow << 2;                   // tile pixel-row base (4 tall)
    const int tc8  = tcol << 3;                   // tile pixel-col base (8 wide)
    const int t    = threadIdx.x;                 // 0..255
    const int l    = t & 63;
    const int wid  = t >> 6;                      // wave 0..3

    const int sh = 6 - lvl;
    const int W2 = 1 << sh;

    for (int i = t; i < 32 * 104; i += 256)
        ((float*)sD)[i] = 0.0f;

    if (t < 32) {
        const int hwc = ((tr4 + (t >> 3)) << 6) + tc8 + (t & 7);
        const float sc = 1.0f / (float)(1 << lvl);
        const float xs = coords[((size_t)b * 2 + 0) * HWP + hwc] * sc;
        const float ys = coords[((size_t)b * 2 + 1) * HWP + hwc] * sc;
        const float x0f = floorf(xs), y0f = floorf(ys);
        sIx[t] = (int)x0f; sIy[t] = (int)y0f;
        const float fx = xs - x0f, fy = ys - y0f;
        sW[t][0] = (1.f - fx) * (1.f - fy);
        sW[t][1] = fx * (1.f - fy);
        sW[t][2] = (1.f - fx) * fy;
        sW[t][3] = fx * fy;
    }
    __syncthreads();
    if (t == 0) {
        int rlo = 1 << 20, rhi = -(1 << 20), clo = 1 << 20, chi = -(1 << 20);
        for (int px = 0; px < 32; ++px) {
            rlo = min(rlo, sIy[px]); rhi = max(rhi, sIy[px]);
            clo = min(clo, sIx[px]); chi = max(chi, sIx[px]);
        }
        const int rl = max(rlo - RADIUS, 0);
        const int rh = min(rhi + RADIUS + 1, W2 - 1);
        const int cf = max(clo - RADIUS, 0);
        const int ce = min(chi + RADIUS + 1, W2 - 1);
        const int nr = rh - rl + 1;
        const int nt = (ce >= cf) ? ((ce - cf + 16) >> 4) : 0;
        sBox[0] = rl;
        sBox[1] = cf;
        sBox[2] = nt;
        sBox[3] = (nr > 0) ? nr * nt : 0;
        sBox[4] = 65535 / max(nt, 1) + 1;     // exact u/nt = (u*inv)>>16 for u<512,nt<=8
    }

    // A fragments for BOTH 16-px sets (verified R9 mapping): lane l = px (l&15), k-chunk (l>>4)
    const int hwA0 = ((tr4 + ((l & 15) >> 3)) << 6) + tc8 + (l & 7);          // px 0..15
    const int hwA1 = ((tr4 + 2 + ((l & 15) >> 3)) << 6) + tc8 + (l & 7);      // px 16..31
    const char* ap0 = wsB + OFF_F1T + ((size_t)(b * HWP + hwA0)) * 512 + ((l >> 4) << 4);
    const char* ap1 = wsB + OFF_F1T + ((size_t)(b * HWP + hwA1)) * 512 + ((l >> 4) << 4);
    const f16x8 a00 = __builtin_bit_cast(f16x8, *(const f32x4*)(ap0));
    const f16x8 a01 = __builtin_bit_cast(f16x8, *(const f32x4*)(ap0 + 64));
    const f16x8 a02 = __builtin_bit_cast(f16x8, *(const f32x4*)(ap0 + 128));
    const f16x8 a03 = __builtin_bit_cast(f16x8, *(const f32x4*)(ap0 + 192));
    const f16x8 a04 = __builtin_bit_cast(f16x8, *(const f32x4*)(ap0 + 256));
    const f16x8 a05 = __builtin_bit_cast(f16x8, *(const f32x4*)(ap0 + 320));
    const f16x8 a06 = __builtin_bit_cast(f16x8, *(const f32x4*)(ap0 + 384));
    const f16x8 a07 = __builtin_bit_cast(f16x8, *(const f32x4*)(ap0 + 448));
    const f16x8 a10 = __builtin_bit_cast(f16x8, *(const f32x4*)(ap1));
    const f16x8 a11 = __builtin_bit_cast(f16x8, *(const f32x4*)(ap1 + 64));
    const f16x8 a12 = __builtin_bit_cast(f16x8, *(const f32x4*)(ap1 + 128));
    const f16x8 a13 = __builtin_bit_cast(f16x8, *(const f32x4*)(ap1 + 192));
    const f16x8 a14 = __builtin_bit_cast(f16x8, *(const f32x4*)(ap1 + 256));
    const f16x8 a15 = __builtin_bit_cast(f16x8, *(const f32x4*)(ap1 + 320));
    const f16x8 a16 = __builtin_bit_cast(f16x8, *(const f32x4*)(ap1 + 384));
    const f16x8 a17 = __builtin_bit_cast(f16x8, *(const f32x4*)(ap1 + 448));
    __syncthreads();                      // publish sBox (also drains A-loads)

    const int rlo = sBox[0], cfi = sBox[1], ntw = sBox[2];
    const int ntot = sBox[3], inv = sBox[4];
    const unsigned lvbase = ((lvl == 0) ? OFF_L0 : (lvl == 1) ? OFF_L1
                           : (lvl == 2) ? OFF_L2 : OFF_L3)
                          + (((unsigned)b << (2 * sh)) << 9);
    const int coff = l & 15;
    const int ksub = (l >> 4) << 4;
    const unsigned zp = OFF_ZPAD + (unsigned)ksub;

    const int pg0 = (l >> 4) << 2;       // scatter pixels of A-set 0 (this lane)
    const int pg1 = 16 + pg0;            // scatter pixels of A-set 1
    const int iy0 = sIy[pg0 + 0], ix0 = sIx[pg0 + 0];
    const int iy1 = sIy[pg0 + 1], ix1 = sIx[pg0 + 1];
    const int iy2 = sIy[pg0 + 2], ix2 = sIx[pg0 + 2];
    const int iy3 = sIy[pg0 + 3], ix3 = sIx[pg0 + 3];
    const int iy4 = sIy[pg1 + 0], ix4 = sIx[pg1 + 0];
    const int iy5 = sIy[pg1 + 1], ix5 = sIx[pg1 + 1];
    const int iy6 = sIy[pg1 + 2], ix6 = sIx[pg1 + 2];
    const int iy7 = sIy[pg1 + 3], ix7 = sIx[pg1 + 3];

    // drain all compiler-tracked VMEM so in-loop vmcnt counts ONLY our asm loads
    asm volatile("s_waitcnt vmcnt(0)" ::: "memory");
    __builtin_amdgcn_sched_barrier(0);

#define DECODE(U_, RR_, JJ_) { const unsigned q__ = ((unsigned)((U_) * inv)) >> 16; \
        JJ_ = (U_) - (int)q__ * ntw; RR_ = rlo + (int)q__; }

// issue one unit's 8 loads via volatile asm (compiler cannot sink/coalesce these)
#define ISSUE(R_, J_, B0, B1, B2, B3, B4, B5, B6, B7) { \
        const int col_ = cfi + ((J_) << 4) + coff; \
        const bool ok_ = (unsigned)col_ < (unsigned)W2; \
        const unsigned cb_ = ok_ ? (lvbase + ((unsigned)(((R_) << sh) + col_) << 9) + (unsigned)ksub) : zp; \
        const char* gp_ = wsB + cb_; \
        asm volatile("global_load_dwordx4 %0, %1, off"            : "=v"(B0) : "v"(gp_)); \
        asm volatile("global_load_dwordx4 %0, %1, off offset:64"  : "=v"(B1) : "v"(gp_)); \
        asm volatile("global_load_dwordx4 %0, %1, off offset:128" : "=v"(B2) : "v"(gp_)); \
        asm volatile("global_load_dwordx4 %0, %1, off offset:192" : "=v"(B3) : "v"(gp_)); \
        asm volatile("global_load_dwordx4 %0, %1, off offset:256" : "=v"(B4) : "v"(gp_)); \
        asm volatile("global_load_dwordx4 %0, %1, off offset:320" : "=v"(B5) : "v"(gp_)); \
        asm volatile("global_load_dwordx4 %0, %1, off offset:384" : "=v"(B6) : "v"(gp_)); \
        asm volatile("global_load_dwordx4 %0, %1, off offset:448" : "=v"(B7) : "v"(gp_)); }

#define WAITV8 { asm volatile("s_waitcnt vmcnt(8)" ::: "memory"); __builtin_amdgcn_sched_barrier(0); }
#define WAITV0 { asm volatile("s_waitcnt vmcnt(0)" ::: "memory"); __builtin_amdgcn_sched_barrier(0); }

// consume one unit against BOTH A-sets: 16 MFMA, scatter 8 px
#define CONSUMET(R_, J_, B0, B1, B2, B3, B4, B5, B6, B7) { \
        f32x4 ac00 = {0.f,0.f,0.f,0.f}, ac01 = {0.f,0.f,0.f,0.f}; \
        f32x4 ac10 = {0.f,0.f,0.f,0.f}, ac11 = {0.f,0.f,0.f,0.f}; \
        ac00 = __builtin_amdgcn_mfma_f32_16x16x32_f16(a00, __builtin_bit_cast(f16x8, B0), ac00, 0, 0, 0); \
        ac10 = __builtin_amdgcn_mfma_f32_16x16x32_f16(a10, __builtin_bit_cast(f16x8, B0), ac10, 0, 0, 0); \
        ac01 = __builtin_amdgcn_mfma_f32_16x16x32_f16(a01, __builtin_bit_cast(f16x8, B1), ac01, 0, 0, 0); \
        ac11 = __builtin_amdgcn_mfma_f32_16x16x32_f16(a11, __builtin_bit_cast(f16x8, B1), ac11, 0, 0, 0); \
        ac00 = __builtin_amdgcn_mfma_f32_16x16x32_f16(a02, __builtin_bit_cast(f16x8, B2), ac00, 0, 0, 0); \
        ac10 = __builtin_amdgcn_mfma_f32_16x16x32_f16(a12, __builtin_bit_cast(f16x8, B2), ac10, 0, 0, 0); \
        ac01 = __builtin_amdgcn_mfma_f32_16x16x32_f16(a03, __builtin_bit_cast(f16x8, B3), ac01, 0, 0, 0); \
        ac11 = __builtin_amdgcn_mfma_f32_16x16x32_f16(a13, __builtin_bit_cast(f16x8, B3), ac11, 0, 0, 0); \
        ac00 = __builtin_amdgcn_mfma_f32_16x16x32_f16(a04, __builtin_bit_cast(f16x8, B4), ac00, 0, 0, 0); \
        ac10 = __builtin_amdgcn_mfma_f32_16x16x32_f16(a14, __builtin_bit_cast(f16x8, B4), ac10, 0, 0, 0); \
        ac01 = __builtin_amdgcn_mfma_f32_16x16x32_f16(a05, __builtin_bit_cast(f16x8, B5), ac01, 0, 0, 0); \
        ac11 = __builtin_amdgcn_mfma_f32_16x16x32_f16(a15, __builtin_bit_cast(f16x8, B5), ac11, 0, 0, 0); \
        ac00 = __builtin_amdgcn_mfma_f32_16x16x32_f16(a06, __builtin_bit_cast(f16x8, B6), ac00, 0, 0, 0); \
        ac10 = __builtin_amdgcn_mfma_f32_16x16x32_f16(a16, __builtin_bit_cast(f16x8, B6), ac10, 0, 0, 0); \
        ac01 = __builtin_amdgcn_mfma_f32_16x16x32_f16(a07, __builtin_bit_cast(f16x8, B7), ac01, 0, 0, 0); \
        ac11 = __builtin_amdgcn_mfma_f32_16x16x32_f16(a17, __builtin_bit_cast(f16x8, B7), ac11, 0, 0, 0); \
        const f32x4 s0 = ac00 + ac01; \
        const f32x4 s1 = ac10 + ac11; \
        const int col_ = cfi + ((J_) << 4) + coff; \
        const int p0 = (R_) - iy0 + RADIUS, q0 = col_ - ix0 + RADIUS; \
        if ((unsigned)p0 < 10u && (unsigned)q0 < 10u) sD[pg0 + 0][p0 * 10 + q0] = s0[0]; \
        const int p1 = (R_) - iy1 + RADIUS, q1 = col_ - ix1 + RADIUS; \
        if ((unsigned)p1 < 10u && (unsigned)q1 < 10u) sD[pg0 + 1][p1 * 10 + q1] = s0[1]; \
        const int p2 = (R_) - iy2 + RADIUS, q2 = col_ - ix2 + RADIUS; \
        if ((unsigned)p2 < 10u && (unsigned)q2 < 10u) sD[pg0 + 2][p2 * 10 + q2] = s0[2]; \
        const int p3 = (R_) - iy3 + RADIUS, q3 = col_ - ix3 + RADIUS; \
        if ((unsigned)p3 < 10u && (unsigned)q3 < 10u) sD[pg0 + 3][p3 * 10 + q3] = s0[3]; \
        const int p4 = (R_) - iy4 + RADIUS, q4 = col_ - ix4 + RADIUS; \
        if ((unsigned)p4 < 10u && (unsigned)q4 < 10u) sD[pg1 + 0][p4 * 10 + q4] = s1[0]; \
        const int p5 = (R_) - iy5 + RADIUS, q5 = col_ - ix5 + RADIUS; \
        if ((unsigned)p5 < 10u && (unsigned)q5 < 10u) sD[pg1 + 1][p5 * 10 + q5] = s1[1]; \
        const int p6 = (R_) - iy6 + RADIUS, q6 = col_ - ix6 + RADIUS; \
        if ((unsigned)p6 < 10u && (unsigned)q6 < 10u) sD[pg1 + 2][p6 * 10 + q6] = s1[2]; \
        const int p7 = (R_) - iy7 + RADIUS, q7 = col_ - ix7 + RADIUS; \
        if ((unsigned)p7 < 10u && (unsigned)q7 < 10u) sD[pg1 + 3][p7 * 10 + q7] = s1[3]; }

    // per-wave ping-pong over units u = wid, wid+4, ... (no barriers in loop)
    {
        f32x4 X0, X1, X2, X3, X4, X5, X6, X7;
        f32x4 Y0, Y1, Y2, Y3, Y4, Y5, Y6, Y7;
        int ua = wid;
        if (ua < ntot) {
            int ra, ja, rb, jb;
            DECODE(ua, ra, ja);
            ISSUE(ra, ja, X0, X1, X2, X3, X4, X5, X6, X7);
            int ub = ua + 4;
            for (;;) {
                const bool bv = (ub < ntot);
                if (bv) { DECODE(ub, rb, jb); ISSUE(rb, jb, Y0, Y1, Y2, Y3, Y4, Y5, Y6, Y7); WAITV8; }
                else    { WAITV0; }
                CONSUMET(ra, ja, X0, X1, X2, X3, X4, X5, X6, X7);
                if (!bv) break;
                ua = ub + 4;
                const bool av = (ua < ntot);
                if (av) { DECODE(ua, ra, ja); ISSUE(ra, ja, X0, X1, X2, X3, X4, X5, X6, X7); WAITV8; }
                else    { WAITV0; }
                CONSUMET(rb, jb, Y0, Y1, Y2, Y3, Y4, Y5, Y6, Y7);
                if (!av) break;
                ub = ua + 4;
            }
        }
    }
#undef DECODE
#undef ISSUE
#undef WAITV8
#undef WAITV0
#undef CONSUMET
    __syncthreads();

    // bilinear combine + store (this level's 81 channels, 32 pixels)
    for (int j = t; j < 32 * KK; j += 256) {
        const int px = j & 31;
        const int k  = j >> 5;           // 0..80
        const int p  = (k * 57) >> 9;    // k/9
        const int q  = k - p * 9;
        const int bi = p * 10 + q;
        const float* dd = sD[px];
        const float v = (sW[px][0] * dd[bi]      + sW[px][1] * dd[bi + 1] +
                         sW[px][2] * dd[bi + 10] + sW[px][3] * dd[bi + 11]) * 0.0625f;
        const int hwp = ((tr4 + (px >> 3)) << 6) + tc8 + (px & 7);
        out[((size_t)b * 324 + lvl * KK + k) * HWP + hwp] = v;
    }
}

// ---------- fallback (Round-2 verified, original layouts) ----------
__global__ __launch_bounds__(128) void corr_level_kernel(
    const float* __restrict__ f1, const float* __restrict__ f2,
    const float* __restrict__ coords, float* __restrict__ out,
    int H2, int W2, float scale, int lvl)
{
    __shared__ float sf1[256];
    __shared__ float sDl[100];
    const int pix = blockIdx.x;
    const int b   = pix >> 12;
    const int hw  = pix & 4095;
    const int t   = threadIdx.x;
    for (int c = t; c < 256; c += 128)
        sf1[c] = f1[((size_t)b * 256 + c) * 4096 + hw];
    __syncthreads();
    const float xs = coords[((size_t)b * 2 + 0) * 4096 + hw] * scale;
    const float ys = coords[((size_t)b * 2 + 1) * 4096 + hw] * scale;
    const float x0f = floorf(xs), y0f = floorf(ys);
    const float fx = xs - x0f, fy = ys - y0f;
    const int ix0 = (int)x0f, iy0 = (int)y0f;
    if (t < 100) {
        const int p = t / 10, q = t - p * 10;
        const int row = iy0 - 4 + p, col = ix0 - 4 + q;
        float acc = 0.0f;
        if (row >= 0 && row < H2 && col >= 0 && col < W2) {
            const size_t step = (size_t)H2 * W2;
            const size_t base = (size_t)b * 256 * step + (size_t)row * W2 + col;
            #pragma unroll 4
            for (int c = 0; c < 256; ++c)
                acc += f2[base + (size_t)c * step] * sf1[c];
        }
        sDl[t] = acc;
    }
    __syncthreads();
    if (t < 81) {
        const int p = t / 9, q = t - p * 9;
        const float d00 = sDl[p * 10 + q];
        const float d01 = sDl[p * 10 + q + 1];
        const float d10 = sDl[p * 10 + q + 10];
        const float d11 = sDl[p * 10 + q + 11];
        const float v = (1.0f - fy) * ((1.0f - fx) * d00 + fx * d01)
                      + fy * ((1.0f - fx) * d10 + fx * d11);
        out[((size_t)b * 324 + (size_t)lvl * 81 + t) * 4096 + hw] = v * 0.0625f;
    }
}

extern "C" void kernel_launch(void* const* d_in, const int* in_sizes, int n_in,
                              void* d_out, int out_size, void* d_ws, size_t ws_size,
                              hipStream_t stream) {
    (void)out_size;
    const float* f1     = (const float*)d_in[0];
    const float* f2l[4] = {(const float*)d_in[1], (const float*)d_in[2],
                           (const float*)d_in[3], (const float*)d_in[4]};
    const float* coords = (const float*)d_in[5];

    // Size-based identification (input order proved unreliable in R1).
    {
        int nbig = 0;
        for (int i = 0; i < n_in; ++i) {
            const int sz = in_sizes[i];
            if (sz == 2097152) {
                if (nbig == 0) f1 = (const float*)d_in[i];
                else           f2l[0] = (const float*)d_in[i];
                ++nbig;
            }
            else if (sz == 524288) f2l[1] = (const float*)d_in[i];
            else if (sz == 131072) f2l[2] = (const float*)d_in[i];
            else if (sz ==  32768) f2l[3] = (const float*)d_in[i];
            else if (sz ==  16384) coords = (const float*)d_in[i];
        }
    }
    float* out = (float*)d_out;
    char*  wsB = (char*)d_ws;

    if (ws_size >= (size_t)OFF_END) {
        stage_kernel<<<dim3(298, 8, 2), dim3(256, 1, 1), 0, stream>>>(
            f1, f2l[0], f2l[1], f2l[2], f2l[3], wsB);
        corr_mfma_kernel<<<dim3(256, 4, 1), 256, 0, stream>>>(wsB, coords, out);
    } else {
        for (int lvl = 0; lvl < 4; ++lvl) {
            const int W2 = 64 >> lvl;
            const float scale = 1.0f / (float)(1 << lvl);
            corr_level_kernel<<<8192, 128, 0, stream>>>(
                f1, f2l[lvl], coords, out, W2, W2, scale, lvl);
        }
    }
}